// Round 1
// baseline (1907.988 us; speedup 1.0000x reference)
//
#include <hip/hip_runtime.h>

#define D_IN 256
#define D_HALF 128

// ---------------- degree kernels ----------------

__global__ void init_deg_kernel(int* __restrict__ in_deg, int* __restrict__ out_deg, int n) {
    int i = blockIdx.x * blockDim.x + threadIdx.x;
    if (i < n) { in_deg[i] = 1; out_deg[i] = 1; }  // self-loop contributes 1 to each
}

__global__ void hist_kernel(const int* __restrict__ col, const int* __restrict__ row,
                            int* __restrict__ in_deg, int* __restrict__ out_deg, int E) {
    int i = blockIdx.x * blockDim.x + threadIdx.x;
    if (i < E) {
        atomicAdd(&in_deg[col[i]], 1);
        atomicAdd(&out_deg[row[i]], 1);
    }
}

__global__ void inv_kernel(const int* __restrict__ in_deg, const int* __restrict__ out_deg,
                           float* __restrict__ inv_in, float* __restrict__ inv_out, int n) {
    int i = blockIdx.x * blockDim.x + threadIdx.x;
    if (i < n) {
        inv_in[i]  = rsqrtf((float)in_deg[i]);   // deg >= 1 always (self-loop)
        inv_out[i] = rsqrtf((float)out_deg[i]);
    }
}

// ---------------- fused GEMM: z[n][c] = x[n] . Wcat[c], Wcat = [W_f; W_b] ----------------
// 64x64 tile, 256 threads, 4x4 micro-tile, K-chunks of 16.

#define TM 64
#define TN 64
#define TK 16

__global__ void gemm_kernel(const float* __restrict__ x,
                            const float* __restrict__ Wf, const float* __restrict__ Wb,
                            float* __restrict__ z, int n_nodes) {
    __shared__ float As[TK][TM + 1];
    __shared__ float Bs[TK][TN + 1];
    const int bm = blockIdx.x * TM;
    const int bn = blockIdx.y * TN;
    const int tid = threadIdx.x;
    const int tm = (tid / 16) * 4;
    const int tn = (tid % 16) * 4;
    float acc[4][4] = {};

    for (int k0 = 0; k0 < D_IN; k0 += TK) {
        // A tile: As[k][m] = x[(bm+m)*256 + k0+k]
        #pragma unroll
        for (int i = tid; i < TM * TK; i += 256) {
            int m = i / TK, k = i % TK;
            int gm = bm + m;
            As[k][m] = (gm < n_nodes) ? x[(long long)gm * D_IN + k0 + k] : 0.f;
        }
        // B tile: Bs[k][n] = Wcat[bn+n][k0+k]
        #pragma unroll
        for (int i = tid; i < TN * TK; i += 256) {
            int n = i / TK, k = i % TK;
            int gn = bn + n;
            const float* Wp = (gn < D_HALF) ? (Wf + (long long)gn * D_IN)
                                            : (Wb + (long long)(gn - D_HALF) * D_IN);
            Bs[k][n] = Wp[k0 + k];
        }
        __syncthreads();
        #pragma unroll
        for (int k = 0; k < TK; ++k) {
            float a[4], b[4];
            #pragma unroll
            for (int i = 0; i < 4; ++i) a[i] = As[k][tm + i];
            #pragma unroll
            for (int j = 0; j < 4; ++j) b[j] = Bs[k][tn + j];
            #pragma unroll
            for (int i = 0; i < 4; ++i)
                #pragma unroll
                for (int j = 0; j < 4; ++j)
                    acc[i][j] += a[i] * b[j];
        }
        __syncthreads();
    }
    #pragma unroll
    for (int i = 0; i < 4; ++i) {
        int gm = bm + tm + i;
        if (gm < n_nodes) {
            #pragma unroll
            for (int j = 0; j < 4; ++j)
                z[(long long)gm * D_IN + bn + tn + j] = acc[i][j];
        }
    }
}

// ---------------- out init: bias + self-loop contribution ----------------
// self-loop edge (i,i): y_fwd[i] += xf[i]*ew_i, y_bwd[i] += xb[i]*ew_i, ew_i = inv_in[i]*inv_out[i]
// With z = [xf | xb] this is uniform: out[n*256+c] = bias[c] + z[n*256+c]*ew_n

__global__ void init_out_kernel(const float* __restrict__ z,
                                const float* __restrict__ inv_in, const float* __restrict__ inv_out,
                                const float* __restrict__ bias,
                                float* __restrict__ out, int n_nodes) {
    int idx = blockIdx.x * blockDim.x + threadIdx.x;
    int total = n_nodes * D_IN;
    if (idx < total) {
        int n = idx >> 8;
        int c = idx & 255;
        float ew = inv_in[n] * inv_out[n];
        out[idx] = bias[c] + z[idx] * ew;
    }
}

// ---------------- edge scatter (atomics) ----------------
// 2 edges per 256-thread block; 128 lanes per edge, each lane does 1 fwd + 1 bwd channel.

__global__ void scatter_kernel(const float* __restrict__ z,
                               const int* __restrict__ col, const int* __restrict__ row,
                               const float* __restrict__ inv_in, const float* __restrict__ inv_out,
                               float* __restrict__ out, int E) {
    int e = blockIdx.x * 2 + (threadIdx.x >> 7);
    int c = threadIdx.x & 127;
    if (e < E) {
        int cn = col[e];
        int rn = row[e];
        float ew = inv_out[rn] * inv_in[cn];
        // forward: mf = xf[rn]*ew -> y_fwd[cn]
        float mf = z[(long long)rn * D_IN + c] * ew;
        atomicAdd(&out[(long long)cn * D_IN + c], mf);
        // backward: mb = xb[cn]*ew -> y_bwd[rn]
        float mb = z[(long long)cn * D_IN + D_HALF + c] * ew;
        atomicAdd(&out[(long long)rn * D_IN + D_HALF + c], mb);
    }
}

// ---------------- launch ----------------

extern "C" void kernel_launch(void* const* d_in, const int* in_sizes, int n_in,
                              void* d_out, int out_size, void* d_ws, size_t ws_size,
                              hipStream_t stream) {
    const float* x    = (const float*)d_in[0];
    const int*   ei   = (const int*)d_in[1];   // [2, E] int32 per harness convention
    const float* Wf   = (const float*)d_in[2];
    const float* Wb   = (const float*)d_in[3];
    const float* bias = (const float*)d_in[4];
    float* out = (float*)d_out;

    const int n_nodes = in_sizes[0] / D_IN;
    const int E = in_sizes[1] / 2;
    const int* col = ei;        // ei[0]
    const int* rowp = ei + E;   // ei[1]

    // workspace layout (needs ~104 MB)
    char* ws = (char*)d_ws;
    float* z = (float*)ws;          ws += (size_t)n_nodes * D_IN * sizeof(float);
    int* in_deg = (int*)ws;         ws += (size_t)n_nodes * sizeof(int);
    int* out_deg = (int*)ws;        ws += (size_t)n_nodes * sizeof(int);
    float* inv_in = (float*)ws;     ws += (size_t)n_nodes * sizeof(float);
    float* inv_out = (float*)ws;    ws += (size_t)n_nodes * sizeof(float);

    init_deg_kernel<<<(n_nodes + 255) / 256, 256, 0, stream>>>(in_deg, out_deg, n_nodes);
    hist_kernel<<<(E + 255) / 256, 256, 0, stream>>>(col, rowp, in_deg, out_deg, E);
    inv_kernel<<<(n_nodes + 255) / 256, 256, 0, stream>>>(in_deg, out_deg, inv_in, inv_out, n_nodes);

    dim3 ggrid((n_nodes + TM - 1) / TM, D_IN / TN);
    gemm_kernel<<<ggrid, 256, 0, stream>>>(x, Wf, Wb, z, n_nodes);

    int total = n_nodes * D_IN;
    init_out_kernel<<<(total + 255) / 256, 256, 0, stream>>>(z, inv_in, inv_out, bias, out, n_nodes);

    scatter_kernel<<<(E + 1) / 2, 256, 0, stream>>>(z, col, rowp, inv_in, inv_out, out, E);
}

// Round 2
// 1037.967 us; speedup vs baseline: 1.8382x; 1.8382x over previous
//
#include <hip/hip_runtime.h>

#define D_IN 256
#define D_HALF 128

// cnt layout: cnt[0..N)   = in-degree-without-selfloop  (count of edges with col==i)
//             cnt[N..2N)  = out-degree-without-selfloop (count of edges with row==i)

__global__ void zero_kernel(int* __restrict__ cnt, int* __restrict__ ctr, int M) {
    int i = blockIdx.x * blockDim.x + threadIdx.x;
    if (i < M) { cnt[i] = 0; ctr[i] = 0; }
}

__global__ void hist_kernel(const int* __restrict__ col, const int* __restrict__ row,
                            int* __restrict__ cnt, int N, int E) {
    int i = blockIdx.x * blockDim.x + threadIdx.x;
    if (i < E) {
        atomicAdd(&cnt[col[i]], 1);
        atomicAdd(&cnt[N + row[i]], 1);
    }
}

__global__ void inv_kernel(const int* __restrict__ cnt,
                           float* __restrict__ inv_in, float* __restrict__ inv_out, int N) {
    int i = blockIdx.x * blockDim.x + threadIdx.x;
    if (i < N) {
        inv_in[i]  = rsqrtf((float)(cnt[i] + 1));      // +1 self-loop; deg >= 1 -> no inf case
        inv_out[i] = rsqrtf((float)(cnt[N + i] + 1));
    }
}

// ---------- exclusive scan of cnt[0..M) -> offs[0..M), 3 passes ----------

__global__ void scan1_kernel(const int* __restrict__ cnt, int* __restrict__ offs,
                             int* __restrict__ blksum, int M) {
    __shared__ int s[256];
    int i = blockIdx.x * 256 + threadIdx.x;
    int v = (i < M) ? cnt[i] : 0;
    s[threadIdx.x] = v;
    __syncthreads();
    for (int d = 1; d < 256; d <<= 1) {
        int t = (threadIdx.x >= d) ? s[threadIdx.x - d] : 0;
        __syncthreads();
        s[threadIdx.x] += t;
        __syncthreads();
    }
    if (i < M) offs[i] = s[threadIdx.x] - v;   // exclusive
    if (threadIdx.x == 255) blksum[blockIdx.x] = s[255];
}

__global__ void scan2_kernel(int* __restrict__ blksum, int nb) {
    __shared__ int s[1024];
    int v = (threadIdx.x < nb) ? blksum[threadIdx.x] : 0;
    s[threadIdx.x] = v;
    __syncthreads();
    for (int d = 1; d < 1024; d <<= 1) {
        int t = (threadIdx.x >= d) ? s[threadIdx.x - d] : 0;
        __syncthreads();
        s[threadIdx.x] += t;
        __syncthreads();
    }
    if (threadIdx.x < nb) blksum[threadIdx.x] = s[threadIdx.x] - v;  // exclusive
}

__global__ void scan3_kernel(int* __restrict__ offs, const int* __restrict__ blksum, int M) {
    int i = blockIdx.x * 256 + threadIdx.x;
    if (i < M) offs[i] += blksum[blockIdx.x];
}

// ---------- CSR fill: adj[offs[col]+k] = row (fwd), adj[offs[N+row]+k] = col (bwd) ----------

__global__ void fill_kernel(const int* __restrict__ col, const int* __restrict__ row,
                            const int* __restrict__ offs, int* __restrict__ ctr,
                            int* __restrict__ adj, int N, int E) {
    int i = blockIdx.x * blockDim.x + threadIdx.x;
    if (i < E) {
        int c = col[i], r = row[i];
        int pf = offs[c] + atomicAdd(&ctr[c], 1);
        adj[pf] = r;
        int pb = offs[N + r] + atomicAdd(&ctr[N + r], 1);
        adj[pb] = c;
    }
}

// ---------------- fused GEMM: z[n][c] = x[n] . Wcat[c], Wcat = [W_f; W_b] ----------------

#define TM 64
#define TN 64
#define TK 16

__global__ void gemm_kernel(const float* __restrict__ x,
                            const float* __restrict__ Wf, const float* __restrict__ Wb,
                            float* __restrict__ z, int n_nodes) {
    __shared__ float As[TK][TM + 1];
    __shared__ float Bs[TK][TN + 1];
    const int bm = blockIdx.x * TM;
    const int bn = blockIdx.y * TN;
    const int tid = threadIdx.x;
    const int tm = (tid / 16) * 4;
    const int tn = (tid % 16) * 4;
    float acc[4][4] = {};

    for (int k0 = 0; k0 < D_IN; k0 += TK) {
        #pragma unroll
        for (int i = tid; i < TM * TK; i += 256) {
            int m = i / TK, k = i % TK;
            int gm = bm + m;
            As[k][m] = (gm < n_nodes) ? x[(long long)gm * D_IN + k0 + k] : 0.f;
        }
        #pragma unroll
        for (int i = tid; i < TN * TK; i += 256) {
            int n = i / TK, k = i % TK;
            int gn = bn + n;
            const float* Wp = (gn < D_HALF) ? (Wf + (long long)gn * D_IN)
                                            : (Wb + (long long)(gn - D_HALF) * D_IN);
            Bs[k][n] = Wp[k0 + k];
        }
        __syncthreads();
        #pragma unroll
        for (int k = 0; k < TK; ++k) {
            float a[4], b[4];
            #pragma unroll
            for (int i = 0; i < 4; ++i) a[i] = As[k][tm + i];
            #pragma unroll
            for (int j = 0; j < 4; ++j) b[j] = Bs[k][tn + j];
            #pragma unroll
            for (int i = 0; i < 4; ++i)
                #pragma unroll
                for (int j = 0; j < 4; ++j)
                    acc[i][j] += a[i] * b[j];
        }
        __syncthreads();
    }
    #pragma unroll
    for (int i = 0; i < 4; ++i) {
        int gm = bm + tm + i;
        if (gm < n_nodes) {
            #pragma unroll
            for (int j = 0; j < 4; ++j)
                z[(long long)gm * D_IN + bn + tn + j] = acc[i][j];
        }
    }
}

// ---------------- gather: one 128-thread block per (node, dir) ----------------
// dir 0 (fwd): neighbors = rows of edges with col==node, weight inv_out[nbr], scale inv_in[node], chan 0..127
// dir 1 (bwd): neighbors = cols of edges with row==node, weight inv_in[nbr], scale inv_out[node], chan 128..255

__global__ void gather_kernel(const float* __restrict__ z, const int* __restrict__ adj,
                              const int* __restrict__ offs, const int* __restrict__ cnt,
                              const float* __restrict__ inv_in, const float* __restrict__ inv_out,
                              const float* __restrict__ bias,
                              float* __restrict__ out, int N) {
    const int node = blockIdx.x;
    const int dir = blockIdx.y;
    const int c = threadIdx.x;          // 0..127
    const int slot = dir * N + node;
    const int beg = offs[slot];
    const int end = beg + cnt[slot];
    const int choff = dir * D_HALF;
    const float* __restrict__ wv = dir ? inv_in : inv_out;
    const float scale = dir ? inv_out[node] : inv_in[node];

    float acc0 = 0.f, acc1 = 0.f;
    int k = beg;
    for (; k + 1 < end; k += 2) {
        int n0 = adj[k], n1 = adj[k + 1];
        float w0 = wv[n0], w1 = wv[n1];
        acc0 += w0 * z[(long long)n0 * D_IN + choff + c];
        acc1 += w1 * z[(long long)n1 * D_IN + choff + c];
    }
    if (k < end) {
        int n0 = adj[k];
        acc0 += wv[n0] * z[(long long)n0 * D_IN + choff + c];
    }
    float acc = acc0 + acc1;

    float invprod = inv_in[node] * inv_out[node];  // self-loop edge weight
    long long oi = (long long)node * D_IN + choff + c;
    out[oi] = bias[choff + c] + invprod * z[oi] + scale * acc;
}

// ---------------- launch ----------------

extern "C" void kernel_launch(void* const* d_in, const int* in_sizes, int n_in,
                              void* d_out, int out_size, void* d_ws, size_t ws_size,
                              hipStream_t stream) {
    const float* x    = (const float*)d_in[0];
    const int*   ei   = (const int*)d_in[1];   // [2, E] int32
    const float* Wf   = (const float*)d_in[2];
    const float* Wb   = (const float*)d_in[3];
    const float* bias = (const float*)d_in[4];
    float* out = (float*)d_out;

    const int N = in_sizes[0] / D_IN;
    const int E = in_sizes[1] / 2;
    const int* col = ei;        // ei[0]
    const int* rowp = ei + E;   // ei[1]

    // workspace layout (~119 MB)
    char* ws = (char*)d_ws;
    float* z = (float*)ws;          ws += (size_t)N * D_IN * sizeof(float);
    int* cnt = (int*)ws;            ws += (size_t)2 * N * sizeof(int);
    int* ctr = (int*)ws;            ws += (size_t)2 * N * sizeof(int);
    int* offs = (int*)ws;           ws += (size_t)2 * N * sizeof(int);
    float* inv_in = (float*)ws;     ws += (size_t)N * sizeof(float);
    float* inv_out = (float*)ws;    ws += (size_t)N * sizeof(float);
    int* adj = (int*)ws;            ws += (size_t)2 * E * sizeof(int);
    int* blksum = (int*)ws;         ws += 1024 * sizeof(int);

    const int M = 2 * N;
    const int nb = (M + 255) / 256;   // 782 <= 1024

    zero_kernel<<<(M + 255) / 256, 256, 0, stream>>>(cnt, ctr, M);
    hist_kernel<<<(E + 255) / 256, 256, 0, stream>>>(col, rowp, cnt, N, E);
    inv_kernel<<<(N + 255) / 256, 256, 0, stream>>>(cnt, inv_in, inv_out, N);

    scan1_kernel<<<nb, 256, 0, stream>>>(cnt, offs, blksum, M);
    scan2_kernel<<<1, 1024, 0, stream>>>(blksum, nb);
    scan3_kernel<<<nb, 256, 0, stream>>>(offs, blksum, M);

    fill_kernel<<<(E + 255) / 256, 256, 0, stream>>>(col, rowp, offs, ctr, adj, N, E);

    dim3 ggrid((N + TM - 1) / TM, D_IN / TN);
    gemm_kernel<<<ggrid, 256, 0, stream>>>(x, Wf, Wb, z, N);

    dim3 grid(N, 2);
    gather_kernel<<<grid, 128, 0, stream>>>(z, adj, offs, cnt, inv_in, inv_out, bias, out, N);
}

// Round 3
// 712.377 us; speedup vs baseline: 2.6783x; 1.4570x over previous
//
#include <hip/hip_runtime.h>

#define D_IN 256
#define D_HALF 128

typedef __attribute__((ext_vector_type(8))) short short8;
typedef __attribute__((ext_vector_type(4))) float float4v;

__device__ __forceinline__ unsigned short f2bf(float f) {
    union { float f; unsigned u; } v; v.f = f;
    unsigned r = v.u + 0x7FFF + ((v.u >> 16) & 1);   // RNE
    return (unsigned short)(r >> 16);
}
__device__ __forceinline__ float bflo(unsigned u) { union { unsigned u; float f; } v; v.u = u << 16; return v.f; }
__device__ __forceinline__ float bfhi(unsigned u) { union { unsigned u; float f; } v; v.u = u & 0xffff0000u; return v.f; }

__device__ __forceinline__ void async16(const void* g, void* l) {
    __builtin_amdgcn_global_load_lds(
        (const __attribute__((address_space(1))) unsigned int*)g,
        (__attribute__((address_space(3))) unsigned int*)l, 16, 0, 0);
}

// ---------------- CSR build ----------------

__global__ void zero_kernel(int* __restrict__ cnt, int* __restrict__ ctr, int M) {
    int i = blockIdx.x * blockDim.x + threadIdx.x;
    if (i < M) { cnt[i] = 0; ctr[i] = 0; }
}

__global__ void hist_kernel(const int* __restrict__ col, const int* __restrict__ row,
                            int* __restrict__ cnt, int N, int E) {
    int i = blockIdx.x * blockDim.x + threadIdx.x;
    if (i < E) {
        atomicAdd(&cnt[col[i]], 1);
        atomicAdd(&cnt[N + row[i]], 1);
    }
}

__global__ void inv_kernel(const int* __restrict__ cnt,
                           float* __restrict__ inv_in, float* __restrict__ inv_out, int N) {
    int i = blockIdx.x * blockDim.x + threadIdx.x;
    if (i < N) {
        inv_in[i]  = rsqrtf((float)(cnt[i] + 1));
        inv_out[i] = rsqrtf((float)(cnt[N + i] + 1));
    }
}

__global__ void scan1_kernel(const int* __restrict__ cnt, int* __restrict__ offs,
                             int* __restrict__ blksum, int M) {
    __shared__ int s[256];
    int i = blockIdx.x * 256 + threadIdx.x;
    int v = (i < M) ? cnt[i] : 0;
    s[threadIdx.x] = v;
    __syncthreads();
    for (int d = 1; d < 256; d <<= 1) {
        int t = (threadIdx.x >= d) ? s[threadIdx.x - d] : 0;
        __syncthreads();
        s[threadIdx.x] += t;
        __syncthreads();
    }
    if (i < M) offs[i] = s[threadIdx.x] - v;
    if (threadIdx.x == 255) blksum[blockIdx.x] = s[255];
}

__global__ void scan2_kernel(int* __restrict__ blksum, int nb) {
    __shared__ int s[1024];
    int v = (threadIdx.x < nb) ? blksum[threadIdx.x] : 0;
    s[threadIdx.x] = v;
    __syncthreads();
    for (int d = 1; d < 1024; d <<= 1) {
        int t = (threadIdx.x >= d) ? s[threadIdx.x - d] : 0;
        __syncthreads();
        s[threadIdx.x] += t;
        __syncthreads();
    }
    if (threadIdx.x < nb) blksum[threadIdx.x] = s[threadIdx.x] - v;
}

__global__ void scan3_kernel(int* __restrict__ offs, const int* __restrict__ blksum, int M) {
    int i = blockIdx.x * 256 + threadIdx.x;
    if (i < M) offs[i] += blksum[blockIdx.x];
}

__global__ void fill_kernel(const int* __restrict__ col, const int* __restrict__ row,
                            const int* __restrict__ offs, int* __restrict__ ctr,
                            int* __restrict__ adj, int N, int E) {
    int i = blockIdx.x * blockDim.x + threadIdx.x;
    if (i < E) {
        int c = col[i], r = row[i];
        int pf = offs[c] + atomicAdd(&ctr[c], 1);
        adj[pf] = r;
        int pb = offs[N + r] + atomicAdd(&ctr[N + r], 1);
        adj[pb] = c;
    }
}

// ---------------- cast x -> bf16, [Wf;Wb] -> bf16 ----------------

__global__ void cast_kernel(const float* __restrict__ x, const float* __restrict__ Wf,
                            const float* __restrict__ Wb, unsigned short* __restrict__ xb,
                            unsigned short* __restrict__ wcat, int n4) {
    int i = blockIdx.x * blockDim.x + threadIdx.x;
    const int w4 = (2 * D_HALF * D_IN) / 4;  // 16384 float4s of Wcat
    if (i < n4) {
        float4 v = ((const float4*)x)[i];
        ushort4 o = { f2bf(v.x), f2bf(v.y), f2bf(v.z), f2bf(v.w) };
        ((ushort4*)xb)[i] = o;
    } else if (i < n4 + w4) {
        int j = i - n4;
        int elem = j * 4;
        const float* src = (elem < D_HALF * D_IN) ? (Wf + elem) : (Wb + (elem - D_HALF * D_IN));
        float4 v = *(const float4*)src;
        ushort4 o = { f2bf(v.x), f2bf(v.y), f2bf(v.z), f2bf(v.w) };
        ((ushort4*)wcat)[j] = o;
    }
}

// ---------------- bf16 MFMA GEMM: zb[m][n] = sum_k xb[m][k] * wcat[n][k] ----------------
// 128x128 tile, BK=32, 256 threads (4 waves, each 64x64), 16x16x32 MFMA.
// LDS XOR swizzle: granule (16B) of (row m, kgran g) stored at m*64B + (g ^ ((m>>1)&3))*16B.
// This keeps global_load_lds's contiguous lane->LDS mapping AND makes the
// quad-strided ds_read_b128 fragment reads 2-way max (free).

#define BM 128
#define BN 128
#define BK 32

__global__ void gemm_mfma_kernel(const unsigned short* __restrict__ xb,
                                 const unsigned short* __restrict__ wcat,
                                 unsigned short* __restrict__ zb, int N) {
    __shared__ __align__(16) unsigned short As[BM * BK];
    __shared__ __align__(16) unsigned short Bs[BN * BK];
    const int tid = threadIdx.x;
    const int wave = tid >> 6;
    const int lane = tid & 63;
    const int bm = blockIdx.x * BM;
    const int bn = blockIdx.y * BN;
    const int warpM = wave >> 1;   // 0..1
    const int warpN = wave & 1;    // 0..1
    const int l15 = lane & 15;
    const int quad = lane >> 4;

    float4v acc[4][4];
    #pragma unroll
    for (int i = 0; i < 4; ++i)
        #pragma unroll
        for (int j = 0; j < 4; ++j)
            acc[i][j] = (float4v){0.f, 0.f, 0.f, 0.f};

    for (int kt = 0; kt < D_IN / BK; ++kt) {
        #pragma unroll
        for (int iss = 0; iss < 2; ++iss) {
            const int pbase = iss * 256 + wave * 64;
            const int p = pbase + lane;
            const int m = p >> 2;
            const int g = (p & 3) ^ ((m >> 1) & 3);
            int gm = bm + m; if (gm >= N) gm = N - 1;
            async16(xb + (size_t)gm * D_IN + kt * BK + g * 8, &As[pbase * 8]);
            async16(wcat + (size_t)(bn + m) * D_IN + kt * BK + g * 8, &Bs[pbase * 8]);
        }
        __syncthreads();

        short8 af[4], bfr[4];
        #pragma unroll
        for (int mi = 0; mi < 4; ++mi) {
            int m = warpM * 64 + mi * 16 + l15;
            af[mi] = *(const short8*)&As[m * BK + (quad ^ ((m >> 1) & 3)) * 8];
        }
        #pragma unroll
        for (int ni = 0; ni < 4; ++ni) {
            int n = warpN * 64 + ni * 16 + l15;
            bfr[ni] = *(const short8*)&Bs[n * BK + (quad ^ ((n >> 1) & 3)) * 8];
        }
        #pragma unroll
        for (int mi = 0; mi < 4; ++mi)
            #pragma unroll
            for (int ni = 0; ni < 4; ++ni)
                acc[mi][ni] = __builtin_amdgcn_mfma_f32_16x16x32_bf16(af[mi], bfr[ni], acc[mi][ni], 0, 0, 0);
        __syncthreads();
    }

    // C/D layout: col = lane&15 (n), row = quad*4 + reg (m)
    #pragma unroll
    for (int mi = 0; mi < 4; ++mi) {
        #pragma unroll
        for (int reg = 0; reg < 4; ++reg) {
            int gm = bm + warpM * 64 + mi * 16 + quad * 4 + reg;
            if (gm < N) {
                #pragma unroll
                for (int ni = 0; ni < 4; ++ni) {
                    int gn = bn + warpN * 64 + ni * 16 + l15;
                    zb[(size_t)gm * D_IN + gn] = f2bf(acc[mi][ni][reg]);
                }
            }
        }
    }
}

// ---------------- gather: one wave per (node, dir), bf16 z ----------------

__global__ void gather_kernel(const unsigned short* __restrict__ zb, const int* __restrict__ adj,
                              const int* __restrict__ offs, const int* __restrict__ cnt,
                              const float* __restrict__ inv_in, const float* __restrict__ inv_out,
                              const float* __restrict__ bias,
                              float* __restrict__ out, int N) {
    const int wave = threadIdx.x >> 6;
    const int lane = threadIdx.x & 63;
    const int slot = blockIdx.x * 4 + wave;
    if (slot >= 2 * N) return;
    const int node = slot >> 1;
    const int dir = slot & 1;
    const int csr = dir * N + node;
    const int beg = offs[csr];
    const int end = beg + cnt[csr];
    const float* __restrict__ wv = dir ? inv_in : inv_out;
    const int choff = dir * D_HALF + 2 * lane;   // two channels per lane

    float a0 = 0.f, a1 = 0.f, b0 = 0.f, b1 = 0.f;
    int k = beg;
    for (; k + 1 < end; k += 2) {
        int n0 = adj[k], n1 = adj[k + 1];
        float w0 = wv[n0], w1 = wv[n1];
        unsigned u0 = *(const unsigned*)&zb[(size_t)n0 * D_IN + choff];
        unsigned u1 = *(const unsigned*)&zb[(size_t)n1 * D_IN + choff];
        a0 += w0 * bflo(u0); a1 += w0 * bfhi(u0);
        b0 += w1 * bflo(u1); b1 += w1 * bfhi(u1);
    }
    if (k < end) {
        int n0 = adj[k];
        float w0 = wv[n0];
        unsigned u0 = *(const unsigned*)&zb[(size_t)n0 * D_IN + choff];
        a0 += w0 * bflo(u0); a1 += w0 * bfhi(u0);
    }
    a0 += b0; a1 += b1;

    const float scale = dir ? inv_out[node] : inv_in[node];
    const float invprod = inv_in[node] * inv_out[node];
    unsigned us = *(const unsigned*)&zb[(size_t)node * D_IN + choff];
    size_t oi = (size_t)node * D_IN + choff;
    float2 o;
    o.x = bias[choff]     + invprod * bflo(us) + scale * a0;
    o.y = bias[choff + 1] + invprod * bfhi(us) + scale * a1;
    *(float2*)&out[oi] = o;
}

// ---------------- launch ----------------

extern "C" void kernel_launch(void* const* d_in, const int* in_sizes, int n_in,
                              void* d_out, int out_size, void* d_ws, size_t ws_size,
                              hipStream_t stream) {
    const float* x    = (const float*)d_in[0];
    const int*   ei   = (const int*)d_in[1];
    const float* Wf   = (const float*)d_in[2];
    const float* Wb   = (const float*)d_in[3];
    const float* bias = (const float*)d_in[4];
    float* out = (float*)d_out;

    const int N = in_sizes[0] / D_IN;
    const int E = in_sizes[1] / 2;
    const int* col = ei;
    const int* rowp = ei + E;

    // workspace (~119 MB)
    char* ws = (char*)d_ws;
    unsigned short* xb = (unsigned short*)ws;   ws += (size_t)N * D_IN * sizeof(short);
    unsigned short* zb = (unsigned short*)ws;   ws += (size_t)N * D_IN * sizeof(short);
    unsigned short* wcat = (unsigned short*)ws; ws += (size_t)2 * D_HALF * D_IN * sizeof(short);
    int* cnt = (int*)ws;            ws += (size_t)2 * N * sizeof(int);
    int* ctr = (int*)ws;            ws += (size_t)2 * N * sizeof(int);
    int* offs = (int*)ws;           ws += (size_t)2 * N * sizeof(int);
    float* inv_in = (float*)ws;     ws += (size_t)N * sizeof(float);
    float* inv_out = (float*)ws;    ws += (size_t)N * sizeof(float);
    int* adj = (int*)ws;            ws += (size_t)2 * E * sizeof(int);
    int* blksum = (int*)ws;         ws += 1024 * sizeof(int);

    const int M = 2 * N;
    const int nb = (M + 255) / 256;

    const int n4 = N * D_IN / 4;
    const int w4 = (2 * D_HALF * D_IN) / 4;
    cast_kernel<<<(n4 + w4 + 255) / 256, 256, 0, stream>>>(x, Wf, Wb, xb, wcat, n4);

    zero_kernel<<<(M + 255) / 256, 256, 0, stream>>>(cnt, ctr, M);
    hist_kernel<<<(E + 255) / 256, 256, 0, stream>>>(col, rowp, cnt, N, E);
    inv_kernel<<<(N + 255) / 256, 256, 0, stream>>>(cnt, inv_in, inv_out, N);

    scan1_kernel<<<nb, 256, 0, stream>>>(cnt, offs, blksum, M);
    scan2_kernel<<<1, 1024, 0, stream>>>(blksum, nb);
    scan3_kernel<<<nb, 256, 0, stream>>>(offs, blksum, M);

    fill_kernel<<<(E + 255) / 256, 256, 0, stream>>>(col, rowp, offs, ctr, adj, N, E);

    dim3 ggrid((N + BM - 1) / BM, D_IN / BN);
    gemm_mfma_kernel<<<ggrid, 256, 0, stream>>>(xb, wcat, zb, N);

    gather_kernel<<<(2 * N + 3) / 4, 256, 0, stream>>>(zb, adj, offs, cnt, inv_in, inv_out, bias, out, N);
}